// Round 2
// baseline (93.971 us; speedup 1.0000x reference)
//
#include <hip/hip_runtime.h>

#define NEG_SLOPE 0.2f
#define EPS 1e-6f

// x: [B=4, C=64, V=3, N=32768] f32, W: [C=64, C=64] f32, out: same as x
// d[b,o,v,n] = sum_i W[o,i] * x[b,i,v,n]
// dot = sum_v x[o]*d[o]; dnsq = sum_v d*d
// out = dot>=0 ? x : x - (1-slope)*(dot/(dnsq+eps))*d

#define C_CH 64
#define V_DIM 3
#define N_FULL 32768
#define NTILE 64
#define THREADS 256

__global__ __launch_bounds__(THREADS, 3)
void vn_leaky_relu_kernel(const float* __restrict__ x,
                          const float* __restrict__ W,
                          float* __restrict__ out) {
    __shared__ float xs[C_CH * V_DIM][NTILE]; // [i*3+v][n]  48 KB (W no longer in LDS)

    const int t   = threadIdx.x;
    const int blk = blockIdx.x;
    const int b   = blk >> 9;           // / 512
    const int n0  = (blk & 511) << 6;   // *64

    const float* xb = x + (size_t)b * (C_CH * V_DIM * N_FULL) + n0;

    // ---- stage x tile: 192 rows x 64 floats = 3072 float4, coalesced
    for (int idx = t; idx < (C_CH * V_DIM * NTILE) / 4; idx += THREADS) {
        int row = idx >> 4;           // 0..191  (i*3+v)
        int c4  = idx & 15;
        float4 v = *(const float4*)(xb + (size_t)row * N_FULL + (c4 << 2));
        *(float4*)&xs[row][c4 << 2] = v;
    }
    __syncthreads();

    const int n = t & 63;  // lane-consecutive n -> conflict-free LDS, coalesced stores
    // wave-uniform o-group, forced through readfirstlane so the compiler
    // proves uniformity and promotes W reads to s_load (scalar pipe, K$)
    const int og = __builtin_amdgcn_readfirstlane(t >> 6);
    const float* __restrict__ Wg = W + (size_t)(og << 4) * C_CH; // 16 rows of W

    float acc[16][3];
    #pragma unroll
    for (int oo = 0; oo < 16; ++oo) {
        acc[oo][0] = 0.f; acc[oo][1] = 0.f; acc[oo][2] = 0.f;
    }

    // inner matvec: per i4 step, 12 b32 LDS x-reads (stride-1 across lanes,
    // conflict-free) + 16 scalar dwordx4 W-reads (uniform addr -> s_load),
    // 192 v_fma_f32 (one SGPR operand each)
    #pragma unroll 4
    for (int i4 = 0; i4 < C_CH / 4; ++i4) {
        float xv[4][3];
        #pragma unroll
        for (int k = 0; k < 4; ++k) {
            #pragma unroll
            for (int v = 0; v < 3; ++v)
                xv[k][v] = xs[(i4 * 4 + k) * 3 + v][n];
        }
        #pragma unroll
        for (int oo = 0; oo < 16; ++oo) {
            float4 w4 = *(const float4*)(Wg + oo * C_CH + (i4 << 2));
            float wk[4] = {w4.x, w4.y, w4.z, w4.w};
            #pragma unroll
            for (int k = 0; k < 4; ++k) {
                acc[oo][0] = fmaf(wk[k], xv[k][0], acc[oo][0]);
                acc[oo][1] = fmaf(wk[k], xv[k][1], acc[oo][1]);
                acc[oo][2] = fmaf(wk[k], xv[k][2], acc[oo][2]);
            }
        }
    }

    // ---- epilogue: leaky projection + coalesced scalar stores
    float* ob = out + (size_t)b * (C_CH * V_DIM * N_FULL) + n0 + n;
    #pragma unroll
    for (int oo = 0; oo < 16; ++oo) {
        const int o = (og << 4) + oo;
        float x0 = xs[o * 3 + 0][n];
        float x1 = xs[o * 3 + 1][n];
        float x2 = xs[o * 3 + 2][n];
        float d0 = acc[oo][0], d1 = acc[oo][1], d2 = acc[oo][2];
        float dot  = x0 * d0 + x1 * d1 + x2 * d2;
        float dnsq = d0 * d0 + d1 * d1 + d2 * d2;
        float f = (1.0f - NEG_SLOPE) * dot / (dnsq + EPS);
        float o0, o1, o2;
        if (dot >= 0.f) {
            o0 = x0; o1 = x1; o2 = x2;
        } else {
            o0 = x0 - f * d0; o1 = x1 - f * d1; o2 = x2 - f * d2;
        }
        float* op = ob + (size_t)o * (V_DIM * N_FULL);
        op[0 * N_FULL] = o0;
        op[1 * N_FULL] = o1;
        op[2 * N_FULL] = o2;
    }
}

extern "C" void kernel_launch(void* const* d_in, const int* in_sizes, int n_in,
                              void* d_out, int out_size, void* d_ws, size_t ws_size,
                              hipStream_t stream) {
    const float* x = (const float*)d_in[0];
    const float* W = (const float*)d_in[1];
    float* out = (float*)d_out;

    const int B = 4;
    const int blocks = B * (N_FULL / NTILE); // 2048
    vn_leaky_relu_kernel<<<blocks, THREADS, 0, stream>>>(x, W, out);
}

// Round 3
// 53.019 us; speedup vs baseline: 1.7724x; 1.7724x over previous
//
#include <hip/hip_runtime.h>

#define NEG_SLOPE 0.2f
#define EPS 1e-6f

// x: [B=4, C=64, V=3, N=32768] f32, W: [C=64, C=64] f32, out like x
// d[b,o,v,n] = sum_i W[o,i]*x[b,i,v,n];  out = dot>=0 ? x : x - 0.8*(dot/(dnsq+eps))*d
//
// MFMA path: per block, n-tile of 64; wave w owns n-sub [w*16, w*16+16).
// d = W·x as 16x16x32 bf16 MFMA, M=64(o) x N=16(n) x K=64(i), per v.
// fp32 accuracy recovered via hi/lo bf16 split (3-product trick).

#define C_CH 64
#define V_DIM 3
#define N_FULL 32768
#define NTILE 64
#define THREADS 256

typedef __attribute__((ext_vector_type(8))) short bf16x8;
typedef __attribute__((ext_vector_type(4))) float f32x4;

__device__ __forceinline__ ushort f2bf(float f) {
    union { float f; unsigned u; } v; v.f = f;
    unsigned r = v.u + 0x7FFFu + ((v.u >> 16) & 1u);  // RNE
    return (ushort)(r >> 16);
}
__device__ __forceinline__ float bf2f(ushort s) {
    union { unsigned u; float f; } v; v.u = ((unsigned)s) << 16; return v.f;
}

__global__ __launch_bounds__(THREADS, 3)
void vn_leaky_relu_mfma(const float* __restrict__ x,
                        const float* __restrict__ W,
                        float* __restrict__ out) {
    __shared__ float xs[C_CH * V_DIM][NTILE];  // [i*3+v][n]  48 KB

    const int t  = threadIdx.x;
    const int b  = blockIdx.x >> 9;          // / 512
    const int n0 = (blockIdx.x & 511) << 6;  // * 64

    const float* xb = x + (size_t)b * (C_CH * V_DIM * N_FULL) + n0;

    // ---- stage x tile fp32: 192 rows x 64 floats, coalesced float4
    for (int idx = t; idx < (C_CH * V_DIM * NTILE) / 4; idx += THREADS) {
        int row = idx >> 4;            // 0..191
        int c4  = idx & 15;
        float4 v = *(const float4*)(xb + (size_t)row * N_FULL + (c4 << 2));
        *(float4*)&xs[row][c4 << 2] = v;
    }

    const int w  = t >> 6;        // wave id 0..3 -> n-sub tile
    const int lo = t & 15;        // lane&15
    const int hi = (t & 63) >> 4; // lane>>4

    // ---- A fragments (W) straight from global (L1-resident, 16 KB total)
    // A[row=lane&15][k=(lane>>4)*8+j], k0 = kh*32 + hi*8
    bf16x8 Ahi[4][2], Alo[4][2];
    #pragma unroll
    for (int m = 0; m < 4; ++m) {
        #pragma unroll
        for (int kh = 0; kh < 2; ++kh) {
            const float* wp = W + (size_t)(m * 16 + lo) * C_CH + kh * 32 + hi * 8;
            float4 wa = *(const float4*)wp;
            float4 wb = *(const float4*)(wp + 4);
            float wf[8] = {wa.x, wa.y, wa.z, wa.w, wb.x, wb.y, wb.z, wb.w};
            bf16x8 h, l;
            #pragma unroll
            for (int j = 0; j < 8; ++j) {
                ushort hb = f2bf(wf[j]);
                h[j] = (short)hb;
                l[j] = (short)f2bf(wf[j] - bf2f(hb));
            }
            Ahi[m][kh] = h; Alo[m][kh] = l;
        }
    }

    f32x4 acc[4][3];
    #pragma unroll
    for (int m = 0; m < 4; ++m)
        #pragma unroll
        for (int v = 0; v < 3; ++v)
            acc[m][v] = (f32x4){0.f, 0.f, 0.f, 0.f};

    __syncthreads();

    // ---- MFMA main: B frag from LDS (fp32 -> bf16 hi/lo), 3-product accumulate
    #pragma unroll
    for (int v = 0; v < 3; ++v) {
        #pragma unroll
        for (int kh = 0; kh < 2; ++kh) {
            float bf[8];
            #pragma unroll
            for (int j = 0; j < 8; ++j)
                bf[j] = xs[(kh * 32 + hi * 8 + j) * V_DIM + v][w * 16 + lo];
            bf16x8 bh, bl;
            #pragma unroll
            for (int j = 0; j < 8; ++j) {
                ushort hb = f2bf(bf[j]);
                bh[j] = (short)hb;
                bl[j] = (short)f2bf(bf[j] - bf2f(hb));
            }
            #pragma unroll
            for (int m = 0; m < 4; ++m) {
                acc[m][v] = __builtin_amdgcn_mfma_f32_16x16x32_bf16(Ahi[m][kh], bh, acc[m][v], 0, 0, 0);
                acc[m][v] = __builtin_amdgcn_mfma_f32_16x16x32_bf16(Ahi[m][kh], bl, acc[m][v], 0, 0, 0);
                acc[m][v] = __builtin_amdgcn_mfma_f32_16x16x32_bf16(Alo[m][kh], bh, acc[m][v], 0, 0, 0);
            }
        }
    }

    // ---- epilogue: C/D layout col=lane&15 (n), row=(lane>>4)*4+reg (o within 16)
    const int nl = w * 16 + lo;
    float* ob = out + (size_t)b * (C_CH * V_DIM * N_FULL) + n0 + nl;
    #pragma unroll
    for (int m = 0; m < 4; ++m) {
        #pragma unroll
        for (int r = 0; r < 4; ++r) {
            const int o = m * 16 + hi * 4 + r;
            float x0 = xs[o * V_DIM + 0][nl];
            float x1 = xs[o * V_DIM + 1][nl];
            float x2 = xs[o * V_DIM + 2][nl];
            float d0 = acc[m][0][r], d1 = acc[m][1][r], d2 = acc[m][2][r];
            float dot  = x0 * d0 + x1 * d1 + x2 * d2;
            float dnsq = d0 * d0 + d1 * d1 + d2 * d2;
            float f = (1.0f - NEG_SLOPE) * dot / (dnsq + EPS);
            float o0, o1, o2;
            if (dot >= 0.f) {
                o0 = x0; o1 = x1; o2 = x2;
            } else {
                o0 = x0 - f * d0; o1 = x1 - f * d1; o2 = x2 - f * d2;
            }
            float* op = ob + (size_t)o * (V_DIM * N_FULL);
            op[0 * N_FULL] = o0;
            op[1 * N_FULL] = o1;
            op[2 * N_FULL] = o2;
        }
    }
}

extern "C" void kernel_launch(void* const* d_in, const int* in_sizes, int n_in,
                              void* d_out, int out_size, void* d_ws, size_t ws_size,
                              hipStream_t stream) {
    const float* x = (const float*)d_in[0];
    const float* W = (const float*)d_in[1];
    float* out = (float*)d_out;

    const int B = 4;
    const int blocks = B * (N_FULL / NTILE);  // 2048
    vn_leaky_relu_mfma<<<blocks, THREADS, 0, stream>>>(x, W, out);
}

// Round 4
// 46.352 us; speedup vs baseline: 2.0273x; 1.1438x over previous
//
#include <hip/hip_runtime.h>

#define NEG_SLOPE 0.2f
#define EPS 1e-6f

// x: [B=4, C=64, V=3, N=32768] f32, W: [64,64] f32, out like x
// d[o,v,n] = sum_i W[o,i]*x[i,v,n]; out = dot>=0 ? x : x - 0.8*(dot/(dnsq+eps))*d
// bf16 MFMA with hi/lo 3-product split for fp32-grade accuracy.

#define C_CH 64
#define V_DIM 3
#define N_FULL 32768
#define NT 32
#define THREADS 256

typedef __attribute__((ext_vector_type(8))) short bf16x8;
typedef __attribute__((ext_vector_type(4))) float f32x4;

__device__ __forceinline__ ushort f2bf(float f) {
    union { float f; unsigned u; } v; v.f = f;
    unsigned r = v.u + 0x7FFFu + ((v.u >> 16) & 1u);  // RNE
    return (ushort)(r >> 16);
}
__device__ __forceinline__ float bf2f(ushort s) {
    union { unsigned u; float f; } v; v.u = ((unsigned)s) << 16; return v.f;
}

// ---- pre-kernel: split W fp32 -> Whi/Wlo bf16 (8 KB each) in workspace
__global__ void w_split_kernel(const float* __restrict__ W,
                               ushort* __restrict__ whi, ushort* __restrict__ wlo) {
    int i = blockIdx.x * 256 + threadIdx.x;
    if (i < C_CH * C_CH) {
        float w = W[i];
        ushort h = f2bf(w);
        whi[i] = h;
        wlo[i] = f2bf(w - bf2f(h));
    }
}

// swizzle: XOR dword-col bits 2-4 with row bits 3-5 (Δrow=24 between hi-groups
// flips row>>3 -> B-frag reads spread across banks; uint4 stays 16B-aligned)
__device__ __forceinline__ int swz(int row) { return ((row >> 3) & 7) << 2; }

template<bool USE_WS>
__global__ __launch_bounds__(THREADS, 5)
void vn_mfma32(const float* __restrict__ x,
               const float* __restrict__ Wf,
               const ushort* __restrict__ whi, const ushort* __restrict__ wlo,
               float* __restrict__ out) {
    __shared__ unsigned xs[C_CH * V_DIM][NT];  // packed (hi<<16)|lo, 24 KB

    const int t    = threadIdx.x;
    const int tile = blockIdx.x;
    const int b    = tile >> 10;            // 1024 tiles per batch
    const int n0   = (tile & 1023) << 5;    // *32

    const float* xb = x + (size_t)b * (C_CH * V_DIM * N_FULL) + n0;

    const int lane = t & 63;
    const int w    = t >> 6;
    const int wo   = w >> 1;   // o-half (0..1) -> 32 rows
    const int wn   = w & 1;    // n-half (0..1) -> 16 cols
    const int l4   = lane & 15;
    const int hi   = lane >> 4;

    // ---- A fragments: Ah/Al[m][kh], row = wo*32+m*16+l4, k = kh*32+hi*8+j
    bf16x8 Ah[2][2], Al[2][2];
    if (USE_WS) {
        #pragma unroll
        for (int m = 0; m < 2; ++m)
            #pragma unroll
            for (int kh = 0; kh < 2; ++kh) {
                size_t off = (size_t)(wo * 32 + m * 16 + l4) * C_CH + kh * 32 + hi * 8;
                Ah[m][kh] = *(const bf16x8*)(whi + off);
                Al[m][kh] = *(const bf16x8*)(wlo + off);
            }
    } else {
        #pragma unroll
        for (int m = 0; m < 2; ++m)
            #pragma unroll
            for (int kh = 0; kh < 2; ++kh) {
                const float* wp = Wf + (size_t)(wo * 32 + m * 16 + l4) * C_CH + kh * 32 + hi * 8;
                float4 wa = *(const float4*)wp;
                float4 wb = *(const float4*)(wp + 4);
                float wf[8] = {wa.x, wa.y, wa.z, wa.w, wb.x, wb.y, wb.z, wb.w};
                bf16x8 h, l;
                #pragma unroll
                for (int j = 0; j < 8; ++j) {
                    ushort hb = f2bf(wf[j]);
                    h[j] = (short)hb;
                    l[j] = (short)f2bf(wf[j] - bf2f(hb));
                }
                Ah[m][kh] = h; Al[m][kh] = l;
            }
    }

    // ---- stage x tile: 192 rows x 32 f32, convert to packed hi|lo u32 once
    #pragma unroll
    for (int it = 0; it < 6; ++it) {
        int idx = t + it * THREADS;      // 0..1535 float4-slots
        int row = idx >> 3;              // 8 float4 per row
        int c4  = (idx & 7) << 2;        // dword col base, bits 2-4
        float4 v = *(const float4*)(xb + (size_t)row * N_FULL + c4);
        float vf[4] = {v.x, v.y, v.z, v.w};
        unsigned p[4];
        #pragma unroll
        for (int q = 0; q < 4; ++q) {
            ushort h = f2bf(vf[q]);
            ushort l = f2bf(vf[q] - bf2f(h));
            p[q] = ((unsigned)h << 16) | l;
        }
        *(uint4*)&xs[row][c4 ^ swz(row)] = *(const uint4*)p;
    }
    __syncthreads();

    f32x4 acc[2][3];
    #pragma unroll
    for (int m = 0; m < 2; ++m)
        #pragma unroll
        for (int v = 0; v < 3; ++v)
            acc[m][v] = (f32x4){0.f, 0.f, 0.f, 0.f};

    // ---- MFMA main: B-frag unpack from packed LDS, 3-product hi/lo
    #pragma unroll
    for (int v = 0; v < 3; ++v) {
        #pragma unroll
        for (int kh = 0; kh < 2; ++kh) {
            bf16x8 bh, bl;
            #pragma unroll
            for (int j = 0; j < 8; ++j) {
                int row = (kh * 32 + hi * 8 + j) * V_DIM + v;
                unsigned p = xs[row][(wn * 16 + l4) ^ swz(row)];
                bh[j] = (short)(p >> 16);
                bl[j] = (short)(p & 0xffffu);
            }
            #pragma unroll
            for (int m = 0; m < 2; ++m) {
                acc[m][v] = __builtin_amdgcn_mfma_f32_16x16x32_bf16(Ah[m][kh], bh, acc[m][v], 0, 0, 0);
                acc[m][v] = __builtin_amdgcn_mfma_f32_16x16x32_bf16(Ah[m][kh], bl, acc[m][v], 0, 0, 0);
                acc[m][v] = __builtin_amdgcn_mfma_f32_16x16x32_bf16(Al[m][kh], bh, acc[m][v], 0, 0, 0);
            }
        }
    }

    // ---- epilogue: C/D col=l4 (n), row=hi*4+r (o within 16)
    const int n = wn * 16 + l4;
    float* ob = out + (size_t)b * (C_CH * V_DIM * N_FULL) + n0 + n;
    #pragma unroll
    for (int m = 0; m < 2; ++m) {
        #pragma unroll
        for (int r = 0; r < 4; ++r) {
            const int o = wo * 32 + m * 16 + hi * 4 + r;
            float xv[3], dv[3];
            #pragma unroll
            for (int v = 0; v < 3; ++v) {
                int row = o * V_DIM + v;
                unsigned p = xs[row][n ^ swz(row)];
                xv[v] = bf2f((ushort)(p >> 16)) + bf2f((ushort)(p & 0xffffu));
                dv[v] = acc[m][v][r];
            }
            float dot  = xv[0] * dv[0] + xv[1] * dv[1] + xv[2] * dv[2];
            float dnsq = dv[0] * dv[0] + dv[1] * dv[1] + dv[2] * dv[2];
            float f = (1.0f - NEG_SLOPE) * dot / (dnsq + EPS);
            float o0, o1, o2;
            if (dot >= 0.f) {
                o0 = xv[0]; o1 = xv[1]; o2 = xv[2];
            } else {
                o0 = xv[0] - f * dv[0]; o1 = xv[1] - f * dv[1]; o2 = xv[2] - f * dv[2];
            }
            float* op = ob + (size_t)o * (V_DIM * N_FULL);
            op[0 * N_FULL] = o0;
            op[1 * N_FULL] = o1;
            op[2 * N_FULL] = o2;
        }
    }
}

extern "C" void kernel_launch(void* const* d_in, const int* in_sizes, int n_in,
                              void* d_out, int out_size, void* d_ws, size_t ws_size,
                              hipStream_t stream) {
    const float* x = (const float*)d_in[0];
    const float* W = (const float*)d_in[1];
    float* out = (float*)d_out;

    const int B = 4;
    const int blocks = B * (N_FULL / NT);  // 4096

    if (ws_size >= 2u * C_CH * C_CH * sizeof(ushort)) {
        ushort* whi = (ushort*)d_ws;
        ushort* wlo = whi + C_CH * C_CH;
        w_split_kernel<<<(C_CH * C_CH + 255) / 256, 256, 0, stream>>>(W, whi, wlo);
        vn_mfma32<true><<<blocks, THREADS, 0, stream>>>(x, W, whi, wlo, out);
    } else {
        vn_mfma32<false><<<blocks, THREADS, 0, stream>>>(x, W, nullptr, nullptr, out);
    }
}